// Round 1
// baseline (745.633 us; speedup 1.0000x reference)
//
#include <hip/hip_runtime.h>
#include <cstdint>
#include <cstddef>

#define K_SAMP 50
#define CAP    4096
#define NFEAT  90
#define RROI   256
#define MROWS  256   // batch rows for BN/MLP

// ---------------------------------------------------------------------------
// Fused: stable per-ROI collection -> FPS (in LDS) -> feature gather
// One block per ROI. 512 threads (8 waves). LDS: 5*16KB = 80KB.
// ---------------------------------------------------------------------------
__global__ __launch_bounds__(512) void roi_fps_feat_kernel(
    const int* __restrict__ idx, const float* __restrict__ coords,
    const float* __restrict__ feats, float* __restrict__ feat_out, int N)
{
    __shared__ float sx[CAP], sy[CAP], sz[CAP], sdist[CAP];
    __shared__ int   sg[CAP];
    __shared__ int   s_wsum[8];
    __shared__ int   s_samp[K_SAMP];
    __shared__ float s_rv[8];
    __shared__ int   s_ri[8];
    __shared__ int   s_last;

    const int r    = blockIdx.x;
    const int tid  = threadIdx.x;
    const int lane = tid & 63;
    const int wid  = tid >> 6;
    const int T    = 512;
    const int VPT  = 8;   // points per thread per chunk (2 x int4)

    // ---- Phase 1: stable collection of this ROI's points (original order) ----
    int base = 0;
    for (int start = 0; start < N; start += T * VPT) {
        int p0 = start + tid * VPT;
        int vals[VPT];
        if (p0 + VPT <= N) {
            const int4* p = reinterpret_cast<const int4*>(idx + p0);
            int4 a = p[0], b = p[1];
            vals[0]=a.x; vals[1]=a.y; vals[2]=a.z; vals[3]=a.w;
            vals[4]=b.x; vals[5]=b.y; vals[6]=b.z; vals[7]=b.w;
        } else {
            #pragma unroll
            for (int j = 0; j < VPT; j++) vals[j] = (p0 + j < N) ? idx[p0 + j] : -1;
        }
        unsigned mmask = 0; int cnt = 0;
        #pragma unroll
        for (int j = 0; j < VPT; j++) {
            bool m = (vals[j] == r);
            mmask |= (m ? 1u : 0u) << j;
            cnt   += m ? 1 : 0;
        }
        // wave inclusive scan of per-thread counts
        int scan = cnt;
        #pragma unroll
        for (int d = 1; d < 64; d <<= 1) {
            int o = __shfl_up(scan, (unsigned)d);
            if (lane >= d) scan += o;
        }
        if (lane == 63) s_wsum[wid] = scan;
        __syncthreads();
        int woff = 0;
        #pragma unroll
        for (int j = 0; j < 8; j++) woff += (j < wid) ? s_wsum[j] : 0;
        int btot = s_wsum[0]+s_wsum[1]+s_wsum[2]+s_wsum[3]
                 + s_wsum[4]+s_wsum[5]+s_wsum[6]+s_wsum[7];
        int w = base + woff + (scan - cnt);   // exclusive position of my first match
        if (mmask) {
            #pragma unroll
            for (int j = 0; j < VPT; j++) {
                if ((mmask >> j) & 1u) {
                    if (w < CAP) {
                        int gi = p0 + j;
                        sg[w] = gi;
                        sx[w] = coords[gi*3 + 0];
                        sy[w] = coords[gi*3 + 1];
                        sz[w] = coords[gi*3 + 2];
                    }
                    w++;
                }
            }
        }
        base += btot;
        __syncthreads();
    }
    const int count = (base < CAP) ? base : CAP;

    // ---- Phase 2: farthest point sampling (matches jnp reference exactly) ----
    if (count > 0) {
        for (int i = tid; i < count; i += T) sdist[i] = 1e10f;
        if (tid == 0) { s_samp[0] = 0; s_last = 0; }
        __syncthreads();
        int last = 0;
        for (int k = 1; k < K_SAMP; k++) {
            float clx = sx[last], cly = sy[last], clz = sz[last];
            float bv = -3.0e38f; int bi = 0x7fffffff;
            for (int i = tid; i < count; i += T) {
                float dx = sx[i] - clx;
                float dy = sy[i] - cly;
                float dz = sz[i] - clz;
                // forbid fma contraction; keep ((x^2+y^2)+z^2) order like the ref
                float d  = __fadd_rn(__fadd_rn(__fmul_rn(dx,dx), __fmul_rn(dy,dy)),
                                     __fmul_rn(dz,dz));
                float nd = fminf(sdist[i], d);
                sdist[i] = nd;
                if (nd > bv || (nd == bv && i < bi)) { bv = nd; bi = i; }
            }
            // wave reduce: max value, min index on ties (== argmax first occurrence)
            #pragma unroll
            for (int m = 32; m > 0; m >>= 1) {
                float ov = __shfl_xor(bv, m);
                int   oi = __shfl_xor(bi, m);
                if (ov > bv || (ov == bv && oi < bi)) { bv = ov; bi = oi; }
            }
            if (lane == 0) { s_rv[wid] = bv; s_ri[wid] = bi; }
            __syncthreads();
            if (tid == 0) {
                #pragma unroll
                for (int j = 1; j < 8; j++) {
                    if (s_rv[j] > bv || (s_rv[j] == bv && s_ri[j] < bi)) {
                        bv = s_rv[j]; bi = s_ri[j];
                    }
                }
                s_samp[k] = bi; s_last = bi;
            }
            __syncthreads();
            last = s_last;
        }
    }
    __syncthreads();

    // ---- Phase 3: gather features of sampled points -> feat row [K_SAMP*NFEAT] ----
    for (int t = tid; t < K_SAMP * NFEAT; t += T) {
        int s = t / NFEAT;
        int f = t - s * NFEAT;
        float v = 0.f;
        if (count > 0) {
            int gid = sg[s_samp[s]];
            v = feats[(size_t)gid * NFEAT + f];
        }
        feat_out[(size_t)r * (K_SAMP * NFEAT) + t] = v;
    }
}

// ---------------------------------------------------------------------------
// fp32 GEMM, C += A[M,K] * B[K,N]; split-K over blockIdx.z with atomicAdd.
// 64x64 tile, 256 threads, 4x4 micro-tile, K-step 16. Biases skipped (BN
// subtracts the column mean, so per-column biases cancel exactly).
// ---------------------------------------------------------------------------
__global__ __launch_bounds__(256) void gemm_splitk(
    const float* __restrict__ A, const float* __restrict__ B, float* __restrict__ C,
    int M, int N, int Kdim, int kc)
{
    __shared__ float As[16][64];  // [k][m]
    __shared__ float Bs[16][64];  // [k][n]
    const int tid = threadIdx.x;
    const int bm  = blockIdx.y * 64;
    const int bn  = blockIdx.x * 64;
    const int k0  = blockIdx.z * kc;
    const int k1  = (k0 + kc < Kdim) ? (k0 + kc) : Kdim;
    const int ty  = tid >> 4, tx = tid & 15;
    const int am  = tid >> 2, ak = (tid & 3) * 4;   // A-tile load mapping
    const int bk  = tid >> 6, bnn = tid & 63;       // B-tile load mapping

    float acc[4][4] = {};
    for (int k = k0; k < k1; k += 16) {
        // A tile (64 rows x 16 k), transposed into As[k][m]
        int arow = bm + am;
        float4 av;
        if (k + ak + 3 < Kdim) {
            av = *reinterpret_cast<const float4*>(A + (size_t)arow * Kdim + k + ak);
        } else {
            av.x = (k+ak+0 < Kdim) ? A[(size_t)arow*Kdim + k+ak+0] : 0.f;
            av.y = (k+ak+1 < Kdim) ? A[(size_t)arow*Kdim + k+ak+1] : 0.f;
            av.z = (k+ak+2 < Kdim) ? A[(size_t)arow*Kdim + k+ak+2] : 0.f;
            av.w = (k+ak+3 < Kdim) ? A[(size_t)arow*Kdim + k+ak+3] : 0.f;
        }
        As[ak+0][am] = av.x; As[ak+1][am] = av.y;
        As[ak+2][am] = av.z; As[ak+3][am] = av.w;
        // B tile (16 k x 64 cols)
        #pragma unroll
        for (int j = 0; j < 4; j++) {
            int kr = bk + j * 4;
            Bs[kr][bnn] = (k + kr < Kdim) ? B[(size_t)(k + kr) * N + bn + bnn] : 0.f;
        }
        __syncthreads();
        #pragma unroll
        for (int kk = 0; kk < 16; kk++) {
            float4 aq = *reinterpret_cast<const float4*>(&As[kk][ty * 4]);
            float4 bq = *reinterpret_cast<const float4*>(&Bs[kk][tx * 4]);
            float a[4] = {aq.x, aq.y, aq.z, aq.w};
            float b[4] = {bq.x, bq.y, bq.z, bq.w};
            #pragma unroll
            for (int i = 0; i < 4; i++)
                #pragma unroll
                for (int j = 0; j < 4; j++)
                    acc[i][j] = fmaf(a[i], b[j], acc[i][j]);
        }
        __syncthreads();
    }
    #pragma unroll
    for (int i = 0; i < 4; i++)
        #pragma unroll
        for (int j = 0; j < 4; j++)
            atomicAdd(&C[(size_t)(bm + ty*4 + i) * N + (bn + tx*4 + j)], acc[i][j]);
}

// ---------------------------------------------------------------------------
// Fused BatchNorm1d (training: biased batch var, eps=1e-5) + optional ReLU.
// One block per column; 256 threads == 256 batch rows. Two-pass stats.
// ---------------------------------------------------------------------------
__global__ __launch_bounds__(256) void bn_kernel(
    const float* __restrict__ X, float* __restrict__ Y,
    const float* __restrict__ g, const float* __restrict__ be, int C, int relu)
{
    const int c = blockIdx.x, t = threadIdx.x;
    const int lane = t & 63, w = t >> 6;
    __shared__ float sw[4], sq[4];

    float x = X[(size_t)t * C + c];
    float s = x;
    #pragma unroll
    for (int d = 32; d > 0; d >>= 1) s += __shfl_xor(s, d);
    if (lane == 0) sw[w] = s;
    __syncthreads();
    float m = (sw[0] + sw[1] + sw[2] + sw[3]) * (1.f / MROWS);
    float dv = x - m;
    float q = dv * dv;
    #pragma unroll
    for (int d = 32; d > 0; d >>= 1) q += __shfl_xor(q, d);
    if (lane == 0) sq[w] = q;
    __syncthreads();
    float v = (sq[0] + sq[1] + sq[2] + sq[3]) * (1.f / MROWS);
    float y = g[c] * dv * rsqrtf(v + 1e-5f) + be[c];
    if (relu) y = fmaxf(y, 0.f);
    Y[(size_t)t * C + c] = y;
}

// ---------------------------------------------------------------------------
extern "C" void kernel_launch(void* const* d_in, const int* in_sizes, int n_in,
                              void* d_out, int out_size, void* d_ws, size_t ws_size,
                              hipStream_t stream)
{
    (void)n_in; (void)out_size; (void)ws_size;
    const int*   idx    = (const int*)  d_in[1];
    const float* feats  = (const float*)d_in[2];
    const float* coords = (const float*)d_in[3];
    const float* w1 = (const float*)d_in[4];
    const float* g1 = (const float*)d_in[6];  const float* be1 = (const float*)d_in[7];
    const float* w2 = (const float*)d_in[8];
    const float* g2 = (const float*)d_in[10]; const float* be2 = (const float*)d_in[11];
    const float* w3 = (const float*)d_in[12];
    const float* g3 = (const float*)d_in[14]; const float* be3 = (const float*)d_in[15];
    const float* w4 = (const float*)d_in[16];
    const float* g4 = (const float*)d_in[18]; const float* be4 = (const float*)d_in[19];
    const float* w5 = (const float*)d_in[20];
    const float* g5 = (const float*)d_in[22]; const float* be5 = (const float*)d_in[23];
    const int N = in_sizes[1];

    float* ws   = (float*)d_ws;
    float* feat = ws;                       // 256*4500 = 1,152,000 floats
    float* x1   = ws + 1152000;             // 65536
    float* y1   = x1 + 65536;               // 65536
    float* x2   = y1 + 65536;               // 65536
    float* y2   = x2 + 65536;               // 65536
    float* x3   = y2 + 65536;               // 131072
    float* y3   = x3 + 131072;              // 131072
    float* x4   = y3 + 131072;              // 65536
    float* y4   = x4 + 65536;               // 65536
    float* x5   = y4 + 65536;               // 131072
    float* out  = (float*)d_out;

    // zero all split-K accumulation buffers (x1..x5 region, 3 MB contiguous)
    hipMemsetAsync(x1, 0, (size_t)(65536*6 + 131072*3) * sizeof(float), stream);

    roi_fps_feat_kernel<<<RROI, 512, 0, stream>>>(idx, coords, feats, feat, N);

    // L1: feat[256,4500] @ w1[4500,256]
    gemm_splitk<<<dim3(4,4,16), 256, 0, stream>>>(feat, w1, x1, 256, 256, 4500, 288);
    bn_kernel  <<<256, 256, 0, stream>>>(x1, y1, g1, be1, 256, 1);
    // L2: [256,256] @ [256,256]
    gemm_splitk<<<dim3(4,4,2), 256, 0, stream>>>(y1, w2, x2, 256, 256, 256, 128);
    bn_kernel  <<<256, 256, 0, stream>>>(x2, y2, g2, be2, 256, 1);
    // L3: [256,256] @ [256,512], no ReLU
    gemm_splitk<<<dim3(8,4,2), 256, 0, stream>>>(y2, w3, x3, 256, 512, 256, 128);
    bn_kernel  <<<512, 256, 0, stream>>>(x3, y3, g3, be3, 512, 0);
    // L4: [256,512] @ [512,256]
    gemm_splitk<<<dim3(4,4,4), 256, 0, stream>>>(y3, w4, x4, 256, 256, 512, 128);
    bn_kernel  <<<256, 256, 0, stream>>>(x4, y4, g4, be4, 256, 1);
    // L5: [256,256] @ [256,512]
    gemm_splitk<<<dim3(8,4,2), 256, 0, stream>>>(y4, w5, x5, 256, 512, 256, 128);
    bn_kernel  <<<512, 256, 0, stream>>>(x5, out, g5, be5, 512, 1);
}

// Round 2
// 559.972 us; speedup vs baseline: 1.3316x; 1.3316x over previous
//
#include <hip/hip_runtime.h>
#include <cstdint>
#include <cstddef>

#define K_SAMP 50
#define CAP    4096
#define NFEAT  90
#define RROI   256
#define MROWS  256
#define CHUNK  1024
#define FROW   (K_SAMP * NFEAT)   // 4500

// ---------------------------------------------------------------------------
// 1) Per-chunk ROI histogram + global per-ROI counts. Reads idx exactly once.
// ---------------------------------------------------------------------------
__global__ __launch_bounds__(256) void hist_kernel(
    const int* __restrict__ idx, int* __restrict__ H, int* __restrict__ counts,
    int N, int nC)
{
    __shared__ int h[RROI];
    const int c = blockIdx.x, tid = threadIdx.x;
    h[tid] = 0;
    __syncthreads();
    int p0 = c * CHUNK + tid * 4;
    if (p0 + 3 < N) {
        int4 v = *reinterpret_cast<const int4*>(idx + p0);
        atomicAdd(&h[v.x], 1); atomicAdd(&h[v.y], 1);
        atomicAdd(&h[v.z], 1); atomicAdd(&h[v.w], 1);
    } else {
        #pragma unroll
        for (int j = 0; j < 4; j++)
            if (p0 + j < N) atomicAdd(&h[idx[p0 + j]], 1);
    }
    __syncthreads();
    int v = h[tid];
    H[tid * nC + c] = v;            // layout [roi][chunk]
    if (v) atomicAdd(&counts[tid], v);
}

// ---------------------------------------------------------------------------
// block-wide exclusive scan over 256 values (4 waves)
// ---------------------------------------------------------------------------
__device__ __forceinline__ int block_scan256(int v, int& total, int* s_w, int tid)
{
    const int lane = tid & 63, w = tid >> 6;
    int inc = v;
    #pragma unroll
    for (int d = 1; d < 64; d <<= 1) {
        int o = __shfl_up(inc, (unsigned)d);
        if (lane >= d) inc += o;
    }
    if (lane == 63) s_w[w] = inc;
    __syncthreads();
    int woff = 0;
    #pragma unroll
    for (int j = 0; j < 4; j++) woff += (j < w) ? s_w[j] : 0;
    total = s_w[0] + s_w[1] + s_w[2] + s_w[3];
    __syncthreads();
    return woff + inc - v;
}

// ---------------------------------------------------------------------------
// 2) One block per ROI: exclusive scan of its chunk hist, + global ROI offset
//    (each block redundantly scans counts[256] — cheap, saves a kernel).
//    After this, H[r][c] = absolute base index for ROI r's points in chunk c.
// ---------------------------------------------------------------------------
__global__ __launch_bounds__(256) void chunk_scan_kernel(
    int* __restrict__ H, const int* __restrict__ counts, int* __restrict__ offs, int nC)
{
    __shared__ int s_w[4];
    __shared__ int s_scan[RROI];
    const int r = blockIdx.x, tid = threadIdx.x;
    int tot;
    int e = block_scan256(counts[tid], tot, s_w, tid);
    s_scan[tid] = e;
    __syncthreads();
    const int off = s_scan[r];
    int v0 = (tid < nC) ? H[r * nC + tid] : 0;
    int t0;
    int e0 = block_scan256(v0, t0, s_w, tid);
    if (tid < nC) H[r * nC + tid] = off + e0;
    int c2 = 256 + tid;
    int v1 = (c2 < nC) ? H[r * nC + c2] : 0;
    int t1;
    int e1 = block_scan256(v1, t1, s_w, tid);
    if (c2 < nC) H[r * nC + c2] = off + t0 + e1;
    if (tid == 0) offs[r] = off;
}

// ---------------------------------------------------------------------------
// 3) Stable scatter: each point -> its ROI segment, preserving original order.
//    In-wave rank via bitwise ballot-match; waves/sub-iters serialized in
//    original point order so the result equals a stable argsort by ROI.
// ---------------------------------------------------------------------------
__global__ __launch_bounds__(256) void scatter_kernel(
    const int* __restrict__ idx, const float* __restrict__ coords,
    const int* __restrict__ H, int* __restrict__ sGid,
    float* __restrict__ sXc, float* __restrict__ sYc, float* __restrict__ sZc,
    int N, int nC)
{
    __shared__ int s_base[RROI];
    const int c = blockIdx.x, tid = threadIdx.x;
    const int lane = tid & 63, wid = tid >> 6;
    s_base[tid] = H[tid * nC + c];
    int roiA[4]; float cxA[4], cyA[4], czA[4]; bool valA[4];
    #pragma unroll
    for (int j = 0; j < 4; j++) {
        int p = c * CHUNK + j * 256 + tid;
        bool v = p < N;
        valA[j] = v;
        roiA[j] = v ? idx[p] : 0;
        float x = 0.f, y = 0.f, z = 0.f;
        if (v) { x = coords[(size_t)p*3]; y = coords[(size_t)p*3+1]; z = coords[(size_t)p*3+2]; }
        cxA[j] = x; cyA[j] = y; czA[j] = z;
    }
    __syncthreads();
    #pragma unroll
    for (int j = 0; j < 4; j++) {
        #pragma unroll
        for (int w = 0; w < 4; w++) {
            if (wid == w) {
                bool v = valA[j];
                int roi = roiA[j];
                unsigned long long vm = __ballot(v);
                unsigned long long match = vm;
                #pragma unroll
                for (int b = 0; b < 8; b++) {
                    unsigned long long vote = __ballot((roi >> b) & 1);
                    match &= ((roi >> b) & 1) ? vote : ~vote;
                }
                int leader = match ? (__ffsll(match) - 1) : 0;
                int gsz  = (int)__popcll(match);
                int rank = (int)__popcll(match & ((1ull << lane) - 1ull));
                int basev = 0;
                if (match && lane == leader) {          // leader is always a valid lane
                    basev = s_base[roi];
                    s_base[roi] = basev + gsz;
                }
                basev = __shfl(basev, leader);
                if (v) {
                    int dest = basev + rank;
                    int p = c * CHUNK + j * 256 + tid;
                    sGid[dest] = p;
                    sXc[dest] = cxA[j]; sYc[dest] = cyA[j]; sZc[dest] = czA[j];
                }
            }
            __syncthreads();
        }
    }
}

// ---------------------------------------------------------------------------
// 4) FPS per ROI (coalesced segment load, register-resident distances) +
//    feature gather. Arithmetic identical to the verified round-1 kernel.
// ---------------------------------------------------------------------------
__global__ __launch_bounds__(512) void fps_feat_kernel(
    const int* __restrict__ offs, const int* __restrict__ counts,
    const float* __restrict__ sXc, const float* __restrict__ sYc,
    const float* __restrict__ sZc, const int* __restrict__ sGid,
    const float* __restrict__ feats, float* __restrict__ feat_out)
{
    __shared__ float sx[CAP], sy[CAP], sz[CAP];
    __shared__ int   sg[CAP];
    __shared__ int   s_samp[K_SAMP];
    __shared__ float s_rv[8];
    __shared__ int   s_ri[8];
    __shared__ int   s_last;

    const int r = blockIdx.x, tid = threadIdx.x;
    const int lane = tid & 63, wid = tid >> 6;
    const int off = offs[r];
    int count = counts[r]; if (count > CAP) count = CAP;

    float rx[8], ry[8], rz[8], rd[8];
    #pragma unroll
    for (int j = 0; j < 8; j++) {
        int i = j * 512 + tid;
        bool v = i < count;
        float x = 0.f, y = 0.f, z = 0.f;
        if (v) {
            x = sXc[off + i]; y = sYc[off + i]; z = sZc[off + i];
            sg[i] = sGid[off + i];
        }
        rx[j] = x; ry[j] = y; rz[j] = z;
        rd[j] = v ? 1e10f : -1.0f;
        sx[i] = x; sy[i] = y; sz[i] = z;
    }
    if (tid == 0) { s_samp[0] = 0; s_last = 0; }
    __syncthreads();

    if (count > 0) {
        int last = 0;
        for (int k = 1; k < K_SAMP; k++) {
            float lx = sx[last], ly = sy[last], lz = sz[last];
            float bv = -3.0e38f; int bi = 0x7fffffff;
            #pragma unroll
            for (int j = 0; j < 8; j++) {
                float dx = rx[j] - lx, dy = ry[j] - ly, dz = rz[j] - lz;
                float d = __fadd_rn(__fadd_rn(__fmul_rn(dx,dx), __fmul_rn(dy,dy)),
                                    __fmul_rn(dz,dz));
                float nd = fminf(rd[j], d);
                rd[j] = nd;
                int i = j * 512 + tid;
                if (nd > bv || (nd == bv && i < bi)) { bv = nd; bi = i; }
            }
            #pragma unroll
            for (int m = 32; m > 0; m >>= 1) {
                float ov = __shfl_xor(bv, m);
                int   oi = __shfl_xor(bi, m);
                if (ov > bv || (ov == bv && oi < bi)) { bv = ov; bi = oi; }
            }
            if (lane == 0) { s_rv[wid] = bv; s_ri[wid] = bi; }
            __syncthreads();
            if (tid == 0) {
                #pragma unroll
                for (int j = 1; j < 8; j++)
                    if (s_rv[j] > bv || (s_rv[j] == bv && s_ri[j] < bi)) {
                        bv = s_rv[j]; bi = s_ri[j];
                    }
                s_samp[k] = bi; s_last = bi;
            }
            __syncthreads();
            last = s_last;
        }
    }
    __syncthreads();

    for (int t = tid; t < FROW; t += 512) {
        int s = t / NFEAT;
        int f = t - s * NFEAT;
        float v = 0.f;
        if (count > 0) {
            int gid = sg[s_samp[s]];
            v = feats[(size_t)gid * NFEAT + f];
        }
        feat_out[(size_t)r * FROW + t] = v;
    }
}

// ---------------------------------------------------------------------------
// fp32 split-K GEMM (unchanged from verified round 1). Biases skipped: BN
// subtracts column means, so per-column biases cancel exactly.
// ---------------------------------------------------------------------------
__global__ __launch_bounds__(256) void gemm_splitk(
    const float* __restrict__ A, const float* __restrict__ B, float* __restrict__ C,
    int M, int N, int Kdim, int kc)
{
    __shared__ float As[16][64];
    __shared__ float Bs[16][64];
    const int tid = threadIdx.x;
    const int bm  = blockIdx.y * 64;
    const int bn  = blockIdx.x * 64;
    const int k0  = blockIdx.z * kc;
    const int k1  = (k0 + kc < Kdim) ? (k0 + kc) : Kdim;
    const int ty  = tid >> 4, tx = tid & 15;
    const int am  = tid >> 2, ak = (tid & 3) * 4;
    const int bk  = tid >> 6, bnn = tid & 63;

    float acc[4][4] = {};
    for (int k = k0; k < k1; k += 16) {
        int arow = bm + am;
        float4 av;
        if (k + ak + 3 < Kdim) {
            av = *reinterpret_cast<const float4*>(A + (size_t)arow * Kdim + k + ak);
        } else {
            av.x = (k+ak+0 < Kdim) ? A[(size_t)arow*Kdim + k+ak+0] : 0.f;
            av.y = (k+ak+1 < Kdim) ? A[(size_t)arow*Kdim + k+ak+1] : 0.f;
            av.z = (k+ak+2 < Kdim) ? A[(size_t)arow*Kdim + k+ak+2] : 0.f;
            av.w = (k+ak+3 < Kdim) ? A[(size_t)arow*Kdim + k+ak+3] : 0.f;
        }
        As[ak+0][am] = av.x; As[ak+1][am] = av.y;
        As[ak+2][am] = av.z; As[ak+3][am] = av.w;
        #pragma unroll
        for (int j = 0; j < 4; j++) {
            int kr = bk + j * 4;
            Bs[kr][bnn] = (k + kr < Kdim) ? B[(size_t)(k + kr) * N + bn + bnn] : 0.f;
        }
        __syncthreads();
        #pragma unroll
        for (int kk = 0; kk < 16; kk++) {
            float4 aq = *reinterpret_cast<const float4*>(&As[kk][ty * 4]);
            float4 bq = *reinterpret_cast<const float4*>(&Bs[kk][tx * 4]);
            float a[4] = {aq.x, aq.y, aq.z, aq.w};
            float b[4] = {bq.x, bq.y, bq.z, bq.w};
            #pragma unroll
            for (int i = 0; i < 4; i++)
                #pragma unroll
                for (int j = 0; j < 4; j++)
                    acc[i][j] = fmaf(a[i], b[j], acc[i][j]);
        }
        __syncthreads();
    }
    #pragma unroll
    for (int i = 0; i < 4; i++)
        #pragma unroll
        for (int j = 0; j < 4; j++)
            atomicAdd(&C[(size_t)(bm + ty*4 + i) * N + (bn + tx*4 + j)], acc[i][j]);
}

// ---------------------------------------------------------------------------
// BatchNorm1d (training, biased var, eps=1e-5) + optional ReLU (unchanged).
// ---------------------------------------------------------------------------
__global__ __launch_bounds__(256) void bn_kernel(
    const float* __restrict__ X, float* __restrict__ Y,
    const float* __restrict__ g, const float* __restrict__ be, int C, int relu)
{
    const int c = blockIdx.x, t = threadIdx.x;
    const int lane = t & 63, w = t >> 6;
    __shared__ float sw[4], sq[4];

    float x = X[(size_t)t * C + c];
    float s = x;
    #pragma unroll
    for (int d = 32; d > 0; d >>= 1) s += __shfl_xor(s, d);
    if (lane == 0) sw[w] = s;
    __syncthreads();
    float m = (sw[0] + sw[1] + sw[2] + sw[3]) * (1.f / MROWS);
    float dv = x - m;
    float q = dv * dv;
    #pragma unroll
    for (int d = 32; d > 0; d >>= 1) q += __shfl_xor(q, d);
    if (lane == 0) sq[w] = q;
    __syncthreads();
    float v = (sq[0] + sq[1] + sq[2] + sq[3]) * (1.f / MROWS);
    float y = g[c] * dv * rsqrtf(v + 1e-5f) + be[c];
    if (relu) y = fmaxf(y, 0.f);
    Y[(size_t)t * C + c] = y;
}

// ---------------------------------------------------------------------------
extern "C" void kernel_launch(void* const* d_in, const int* in_sizes, int n_in,
                              void* d_out, int out_size, void* d_ws, size_t ws_size,
                              hipStream_t stream)
{
    (void)n_in; (void)out_size; (void)ws_size;
    const int*   idx    = (const int*)  d_in[1];
    const float* feats  = (const float*)d_in[2];
    const float* coords = (const float*)d_in[3];
    const float* w1 = (const float*)d_in[4];
    const float* g1 = (const float*)d_in[6];  const float* be1 = (const float*)d_in[7];
    const float* w2 = (const float*)d_in[8];
    const float* g2 = (const float*)d_in[10]; const float* be2 = (const float*)d_in[11];
    const float* w3 = (const float*)d_in[12];
    const float* g3 = (const float*)d_in[14]; const float* be3 = (const float*)d_in[15];
    const float* w4 = (const float*)d_in[16];
    const float* g4 = (const float*)d_in[18]; const float* be4 = (const float*)d_in[19];
    const float* w5 = (const float*)d_in[20];
    const float* g5 = (const float*)d_in[22]; const float* be5 = (const float*)d_in[23];
    const int N  = in_sizes[1];
    const int nC = (N + CHUNK - 1) / CHUNK;   // 489 for N=500000 (fits 2 scan rounds)

    float* ws   = (float*)d_ws;
    float* feat = ws;                        // 1,152,000
    float* x1   = ws + 1152000;
    float* y1   = x1 + 65536;
    float* x2   = y1 + 65536;
    float* y2   = x2 + 65536;
    float* x3   = y2 + 65536;
    float* y3   = x3 + 131072;
    float* x4   = y3 + 131072;
    float* y4   = x4 + 65536;
    float* x5   = y4 + 65536;
    int*   counts = (int*)(x5 + 131072);     // 256
    int*   offs   = counts + 256;            // 256
    int*   H      = offs + 256;              // 256*1024 max
    int*   sGid   = H + 256 * 1024;          // N
    float* sXc    = (float*)(sGid + N);      // N
    float* sYc    = sXc + N;                 // N
    float* sZc    = sYc + N;                 // N
    float* out    = (float*)d_out;

    // zero split-K accumulators (x/y region) + counts
    hipMemsetAsync(x1, 0, (size_t)(786432 + 256) * sizeof(float), stream);

    hist_kernel      <<<nC,  256, 0, stream>>>(idx, H, counts, N, nC);
    chunk_scan_kernel<<<256, 256, 0, stream>>>(H, counts, offs, nC);
    scatter_kernel   <<<nC,  256, 0, stream>>>(idx, coords, H, sGid, sXc, sYc, sZc, N, nC);
    fps_feat_kernel  <<<256, 512, 0, stream>>>(offs, counts, sXc, sYc, sZc, sGid, feats, feat);

    gemm_splitk<<<dim3(4,4,16), 256, 0, stream>>>(feat, w1, x1, 256, 256, 4500, 288);
    bn_kernel  <<<256, 256, 0, stream>>>(x1, y1, g1, be1, 256, 1);
    gemm_splitk<<<dim3(4,4,2), 256, 0, stream>>>(y1, w2, x2, 256, 256, 256, 128);
    bn_kernel  <<<256, 256, 0, stream>>>(x2, y2, g2, be2, 256, 1);
    gemm_splitk<<<dim3(8,4,2), 256, 0, stream>>>(y2, w3, x3, 256, 512, 256, 128);
    bn_kernel  <<<512, 256, 0, stream>>>(x3, y3, g3, be3, 512, 0);
    gemm_splitk<<<dim3(4,4,4), 256, 0, stream>>>(y3, w4, x4, 256, 256, 512, 128);
    bn_kernel  <<<256, 256, 0, stream>>>(x4, y4, g4, be4, 256, 1);
    gemm_splitk<<<dim3(8,4,2), 256, 0, stream>>>(y4, w5, x5, 256, 512, 256, 128);
    bn_kernel  <<<512, 256, 0, stream>>>(x5, out, g5, be5, 512, 1);
}